// Round 1
// baseline (910.035 us; speedup 1.0000x reference)
//
#include <hip/hip_runtime.h>

// Problem constants (from reference setup_inputs)
#define B 256
#define K 32
#define D 2048
#define N 100000
#define CHUNK 1024                 // d-elements per block
#define NBLK (B * (D / CHUNK))     // 512 blocks
#define MATCH_WEIGHT 80.0f

__global__ __launch_bounds__(256)
void loss_match_kernel(const float* __restrict__ e,   // [B,K,D]
                       const float* __restrict__ W,   // [D,N]
                       const int*   __restrict__ idx, // [B]
                       float* __restrict__ out)
{
    const int blk = blockIdx.x;
    const int b   = blk >> 1;            // D/CHUNK == 2
    const int d0  = (blk & 1) * CHUNK;
    const int t   = threadIdx.x;

    const int col = idx[b];
    const int d   = d0 + t * 4;          // this thread's 4 d-indices

    // Gather target column values into registers. Strided (uncoalesced by
    // nature: stride N*4 = 400 KB), but each thread needs only these 4 values
    // for ALL 32 k-slices — register reuse, no LDS needed.
    const size_t wbase = (size_t)d * N + (size_t)col;
    const float t0 = W[wbase];
    const float t1 = W[wbase + (size_t)N];
    const float t2 = W[wbase + 2ull * N];
    const float t3 = W[wbase + 3ull * N];

    // Coalesced float4 reads of e over the k dimension.
    const float* ebase = e + (size_t)b * K * D + d0 + (size_t)t * 4;
    float acc = 0.0f;
#pragma unroll 8
    for (int k = 0; k < K; ++k) {
        const float4 v = *(const float4*)(ebase + (size_t)k * D);
        acc += fabsf(v.x - t0) + fabsf(v.y - t1)
             + fabsf(v.z - t2) + fabsf(v.w - t3);
    }

    // Wave(64)-wide shuffle reduction, then cross-wave via LDS.
    for (int off = 32; off > 0; off >>= 1)
        acc += __shfl_down(acc, off, 64);

    __shared__ float wsum[4];            // 256 threads = 4 waves
    const int wave = t >> 6;
    if ((t & 63) == 0) wsum[wave] = acc;
    __syncthreads();

    if (t == 0) {
        const float s = wsum[0] + wsum[1] + wsum[2] + wsum[3];
        // Scale per block so the atomic accumulates the final (small) value.
        const float scale = MATCH_WEIGHT / (float)((size_t)B * K * D);
        atomicAdd(out, s * scale);
    }
}

extern "C" void kernel_launch(void* const* d_in, const int* in_sizes, int n_in,
                              void* d_out, int out_size, void* d_ws, size_t ws_size,
                              hipStream_t stream) {
    const float* e   = (const float*)d_in[0];
    const float* W   = (const float*)d_in[1];
    const int*   idx = (const int*)d_in[2];
    float* out = (float*)d_out;

    // d_out is poisoned to 0xAA before every timed launch — zero it.
    hipMemsetAsync(out, 0, (size_t)out_size * sizeof(float), stream);

    loss_match_kernel<<<NBLK, 256, 0, stream>>>(e, W, idx, out);
}